// Round 8
// baseline (633.885 us; speedup 1.0000x reference)
//
#include <hip/hip_runtime.h>
#include <hip/hip_bf16.h>

// GRU-like fused cell: out = (1-z)*tanh(i_n + r*h_n) + z*e
// B=8, H=512, N=8192. bf16 MFMA 16x16x32, fp32 acc, fused epilogue.
//
// R7 -> R8: R5/R6/R7 identical at ~420us => scheduling-invariant cost. Audit
// found X loads anti-coalesced (lane l at (l&15)*128KB stride -> 32-64 way
// transaction split per instr) and global_load_lds forcing conservative
// vmcnt drains. Redesign staging: (1) X loads fully coalesced (per k-row,
// 64 lanes x float2 contiguous), (2) A reg-staged (loads->regs->ds_write,
// precise per-reg vmcnt, T14), (3) barrier = lgkmcnt(0)+s_barrier only.

#define HH 512
#define NBATCH 8
#define NN 8192
#define BN 128
#define BK 64
#define NSTEPS 16
#define THREADS 256
#define A_BYTES (192 * BK * 2)          // 24576
#define B_BYTES (BN * BK * 2)           // 16384
#define BUF_BYTES (A_BYTES + B_BYTES)   // 40960
#define LDS_TOTAL (2 * BUF_BYTES)       // 81920 -> 2 WGs/CU

typedef __attribute__((ext_vector_type(8))) short short8;
typedef __attribute__((ext_vector_type(4))) float f32x4;

__device__ __forceinline__ unsigned cvt_pk_bf16(float a, float b) {
  unsigned r;
  asm("v_cvt_pk_bf16_f32 %0, %1, %2" : "=v"(r) : "v"(a), "v"(b));
  return r;
}

#define MFMA16(a_, b_, c_) __builtin_amdgcn_mfma_f32_16x16x32_bf16((a_), (b_), (c_), 0, 0, 0)

#define WG_BARRIER() do {                                   \
    asm volatile("s_waitcnt lgkmcnt(0)" ::: "memory");      \
    __builtin_amdgcn_sched_barrier(0);                      \
    __builtin_amdgcn_s_barrier();                           \
    __builtin_amdgcn_sched_barrier(0);                      \
  } while (0)

// ---------------- weight pre-pack (unchanged, verified R1-R7) ----------------
__global__ void prepack_w(const float* __restrict__ W_ih, const float* __restrict__ W_hh,
                          __hip_bfloat16* __restrict__ ws) {
  int t = blockIdx.x * 256 + threadIdx.x;
  int blk = t / 12288;                              // ht*16 + s
  int e = t % 12288;
  int ra = e >> 6;                                  // 0..191
  int kk = (e & 63) ^ ((ra & 7) << 3);              // inverse of read-side XOR swizzle
  int gate = ra >> 6;
  int h = (blk >> 4) * 64 + (ra & 63);
  int row = gate * HH + h;
  int kg = (blk & 15) * 64 + kk;
  float v = (kg < 512) ? W_ih[row * 512 + kg] : W_hh[row * 512 + (kg - 512)];
  ws[t] = __float2bfloat16(v);
}

// ---------------- main fused kernel ----------------
__global__ __launch_bounds__(THREADS, 2)
void gru_main(const float* __restrict__ e_wv, const float* __restrict__ m_wv,
              const __hip_bfloat16* __restrict__ wimg, float* __restrict__ out) {
  extern __shared__ char smem[];
  const int tid  = threadIdx.x;
  const int lane = tid & 63;
  const int wave = tid >> 6;       // 0..3
  const int wm = wave >> 1;        // 0..1 : 32-row half of 64-h tile
  const int wn = wave & 1;         // 0..1 : 64-col half of 128-n tile
  const int KW = wave << 4;        // 16 k-rows of X staged by this wave

  // XCD swizzle (bijective: 4096 % 8 == 0), ht fastest.
  const int wg  = blockIdx.x;
  const int swz = (wg & 7) * 512 + (wg >> 3);
  const int ht  = swz & 7;
  const int nt  = (swz >> 3) & 63;
  const int b   = swz >> 9;

  const size_t batch_off = (size_t)b * HH * NN;
  // X staging base: k-row = KW + g*4 + u (local), n = nt*128 + 2*lane (+1)
  const float* xm = m_wv + batch_off + (size_t)KW * NN + nt * BN + 2 * lane;
  const float* xe = e_wv + batch_off + (size_t)KW * NN + nt * BN + 2 * lane;
  const char*  wA = (const char*)wimg + (size_t)ht * NSTEPS * A_BYTES + tid * 16;

  f32x4 acc_r[2][4]  = {};
  f32x4 acc_z[2][4]  = {};
  f32x4 acc_in[2][4] = {};
  f32x4 acc_hn[2][4] = {};

  uint4  aR[6];     // staged A (bf16 image), 24 VGPRs
  float2 xR[16];    // staged X f32: 4 k-quads x (2 n), 32 VGPRs

  int aoff[2], boff[2];
#pragma unroll
  for (int kb2 = 0; kb2 < 2; ++kb2) {
    const int ke2 = kb2 * 64 + ((lane >> 4) << 4);
    const int sw  = (lane & 7) << 4;
    aoff[kb2] = (wm * 32 + (lane & 15)) * 128 + (ke2 ^ sw);
    boff[kb2] = A_BYTES + (wn * 64 + (lane & 15)) * 128 + (ke2 ^ sw);
  }

  auto issue_AX = [&](int t) {     // global -> regs (fully coalesced)
    const char* gA = wA + (size_t)t * A_BYTES;
#pragma unroll
    for (int i = 0; i < 6; ++i)
      aR[i] = *(const uint4*)(gA + i * 4096);
    const float* xs = (t < 8 ? xm : xe) + (size_t)(t & 7) * (64 * NN);
#pragma unroll
    for (int g = 0; g < 4; ++g)
#pragma unroll
      for (int u = 0; u < 4; ++u)
        xR[g * 4 + u] = *(const float2*)(xs + (size_t)(g * 4 + u) * NN);
  };

  auto write_AX = [&](char* nb) {  // regs -> LDS (precise vmcnt at first use)
    char* lA = nb + tid * 16;
#pragma unroll
    for (int i = 0; i < 6; ++i)
      *(uint4*)(lA + i * 4096) = aR[i];
    char* Bb = nb + A_BYTES;
    const int n0 = 2 * lane;
#pragma unroll
    for (int g = 0; g < 4; ++g) {
      uint2 w0, w1;
      w0.x = cvt_pk_bf16(xR[g * 4 + 0].x, xR[g * 4 + 1].x);   // k0,k1
      w0.y = cvt_pk_bf16(xR[g * 4 + 2].x, xR[g * 4 + 3].x);   // k2,k3
      w1.x = cvt_pk_bf16(xR[g * 4 + 0].y, xR[g * 4 + 1].y);
      w1.y = cvt_pk_bf16(xR[g * 4 + 2].y, xR[g * 4 + 3].y);
      const int kb = (KW + g * 4) * 2;
      *(uint2*)(Bb + n0 * 128 + (kb ^ ((n0 & 7) << 4)))            = w0;
      *(uint2*)(Bb + (n0 + 1) * 128 + (kb ^ (((n0 + 1) & 7) << 4))) = w1;
    }
  };

  auto compute_kb2 = [&](const char* cb, int kb2, bool firstHalf) {
    short8 bfr[4];
#pragma unroll
    for (int ni = 0; ni < 4; ++ni)
      bfr[ni] = *(const short8*)(cb + boff[kb2] + ni * 2048);
    {  // gate r
      short8 a0 = *(const short8*)(cb + aoff[kb2]);
      short8 a1 = *(const short8*)(cb + aoff[kb2] + 2048);
#pragma unroll
      for (int ni = 0; ni < 4; ++ni) {
        acc_r[0][ni] = MFMA16(a0, bfr[ni], acc_r[0][ni]);
        acc_r[1][ni] = MFMA16(a1, bfr[ni], acc_r[1][ni]);
      }
    }
    {  // gate z
      short8 a0 = *(const short8*)(cb + aoff[kb2] + 8192);
      short8 a1 = *(const short8*)(cb + aoff[kb2] + 8192 + 2048);
#pragma unroll
      for (int ni = 0; ni < 4; ++ni) {
        acc_z[0][ni] = MFMA16(a0, bfr[ni], acc_z[0][ni]);
        acc_z[1][ni] = MFMA16(a1, bfr[ni], acc_z[1][ni]);
      }
    }
    {  // gate n -> acc_in (m-phase) / acc_hn (e-phase)
      short8 a0 = *(const short8*)(cb + aoff[kb2] + 16384);
      short8 a1 = *(const short8*)(cb + aoff[kb2] + 16384 + 2048);
      if (firstHalf) {
#pragma unroll
        for (int ni = 0; ni < 4; ++ni) {
          acc_in[0][ni] = MFMA16(a0, bfr[ni], acc_in[0][ni]);
          acc_in[1][ni] = MFMA16(a1, bfr[ni], acc_in[1][ni]);
        }
      } else {
#pragma unroll
        for (int ni = 0; ni < 4; ++ni) {
          acc_hn[0][ni] = MFMA16(a0, bfr[ni], acc_hn[0][ni]);
          acc_hn[1][ni] = MFMA16(a1, bfr[ni], acc_hn[1][ni]);
        }
      }
    }
  };

  // prologue: buf0 <- step0; issue step1; barrier (lgkm only)
  issue_AX(0);
  write_AX(smem);        // precise waits on aR/xR here
  issue_AX(1);           // in flight across barrier + step0 compute
  WG_BARRIER();

#pragma unroll 1
  for (int s = 0; s < NSTEPS; ++s) {
    char* cb = smem + ((s & 1) ? BUF_BYTES : 0);
    char* nb = smem + ((s & 1) ? 0 : BUF_BYTES);
    const bool firstHalf = (s < 8);

    __builtin_amdgcn_s_setprio(1);
    compute_kb2(cb, 0, firstHalf);
    compute_kb2(cb, 1, firstHalf);
    __builtin_amdgcn_s_setprio(0);

    if (s + 1 < NSTEPS) {
      write_AX(nb);                      // consume s+1 regs (had full step of flight)
      if (s + 2 < NSTEPS) issue_AX(s + 2);
      WG_BARRIER();                      // lgkm only -- s+2 loads stay in flight
    }
  }

  // epilogue: gates + blend (unchanged, verified R1-R7)
  const size_t obase = batch_off + (size_t)(ht * 64 + wm * 32) * NN + nt * BN + wn * 64;
  const float* ep = e_wv + obase;
  float* op = out + obase;
  const int rsub = (lane >> 4) << 2;
  const int csub = lane & 15;
#pragma unroll
  for (int mi = 0; mi < 2; ++mi)
#pragma unroll
    for (int ni = 0; ni < 4; ++ni) {
#pragma unroll
      for (int r = 0; r < 4; ++r) {
        size_t idx = (size_t)(mi * 16 + rsub + r) * NN + ni * 16 + csub;
        float pr  = acc_r[mi][ni][r];
        float pz  = acc_z[mi][ni][r];
        float vin = acc_in[mi][ni][r];
        float vhn = acc_hn[mi][ni][r];
        float rr  = 1.f / (1.f + __expf(-pr));
        float zz  = 1.f / (1.f + __expf(-pz));
        float ex  = __expf(2.f * (vin + rr * vhn));
        float nn2 = 1.f - 2.f / (ex + 1.f);      // tanh, inf-safe
        float ev  = ep[idx];
        op[idx] = (1.f - zz) * nn2 + zz * ev;
      }
    }
}

extern "C" void kernel_launch(void* const* d_in, const int* in_sizes, int n_in,
                              void* d_out, int out_size, void* d_ws, size_t ws_size,
                              hipStream_t stream) {
  const float* e_wv = (const float*)d_in[0];
  const float* m_wv = (const float*)d_in[1];
  const float* W_ih = (const float*)d_in[2];
  const float* W_hh = (const float*)d_in[3];
  float* out = (float*)d_out;
  __hip_bfloat16* wimg = (__hip_bfloat16*)d_ws;   // 3 MiB weight image

  (void)hipFuncSetAttribute((const void*)gru_main,
                            hipFuncAttributeMaxDynamicSharedMemorySize, LDS_TOTAL);

  prepack_w<<<(NBATCH * NSTEPS * 12288) / 256, 256, 0, stream>>>(W_ih, W_hh, wimg);
  gru_main<<<NBATCH * 8 * 64, THREADS, LDS_TOTAL, stream>>>(e_wv, m_wv, wimg, out);
}

// Round 9
// 426.340 us; speedup vs baseline: 1.4868x; 1.4868x over previous
//
#include <hip/hip_runtime.h>
#include <hip/hip_bf16.h>

// GRU-like fused cell: out = (1-z)*tanh(i_n + r*h_n) + z*e
// B=8, H=512, N=8192. bf16 MFMA 16x16x32, fp32 acc, fused epilogue.
//
// R8 -> R9: R5-R8 all ~420us = latency-bound invariant; 128 acc regs/thread
// capped occupancy at 2 waves/SIMD. Halve acc via 512-thr WG with same 64x128
// tile (wave tile 32x32, acc 64/thr, demand ~115 regs) -> launch_bounds(512,4)
// = 128-reg cap, 2 WGs x 8 waves = 16 waves/CU. LDS 80KB/WG x2 = 160KB exact.
// Staging = verified-clean R1 patterns (gload_lds A, 4kx4n X, 0 conflicts),
// plain __syncthreads; TLP does the latency hiding.

#define HH 512
#define NBATCH 8
#define NN 8192
#define BN 128
#define BK 64
#define NSTEPS 16
#define THREADS 512
#define A_BYTES (192 * BK * 2)          // 24576
#define B_BYTES (BN * BK * 2)           // 16384
#define BUF_BYTES (A_BYTES + B_BYTES)   // 40960
#define LDS_TOTAL (2 * BUF_BYTES)       // 81920/WG -> 2 WGs/CU = 163840 = full LDS

typedef __attribute__((ext_vector_type(8))) short short8;
typedef __attribute__((ext_vector_type(4))) float f32x4;

__device__ __forceinline__ unsigned cvt_pk_bf16(float a, float b) {
  unsigned r;
  asm("v_cvt_pk_bf16_f32 %0, %1, %2" : "=v"(r) : "v"(a), "v"(b));
  return r;
}

__device__ __forceinline__ void gload_lds16(const void* g, void* l) {
  __builtin_amdgcn_global_load_lds(
      (__attribute__((address_space(1))) void*)(g),
      (__attribute__((address_space(3))) void*)(l), 16, 0, 0);
}

#define MFMA16(a_, b_, c_) __builtin_amdgcn_mfma_f32_16x16x32_bf16((a_), (b_), (c_), 0, 0, 0)

// ---------------- weight pre-pack (unchanged, verified R1-R8) ----------------
__global__ void prepack_w(const float* __restrict__ W_ih, const float* __restrict__ W_hh,
                          __hip_bfloat16* __restrict__ ws) {
  int t = blockIdx.x * 256 + threadIdx.x;
  int blk = t / 12288;                              // ht*16 + s
  int e = t % 12288;
  int ra = e >> 6;                                  // 0..191
  int kk = (e & 63) ^ ((ra & 7) << 3);              // inverse of read-side XOR swizzle
  int gate = ra >> 6;
  int h = (blk >> 4) * 64 + (ra & 63);
  int row = gate * HH + h;
  int kg = (blk & 15) * 64 + kk;
  float v = (kg < 512) ? W_ih[row * 512 + kg] : W_hh[row * 512 + (kg - 512)];
  ws[t] = __float2bfloat16(v);
}

// ---------------- main fused kernel ----------------
__global__ __launch_bounds__(THREADS, 4)   // 4 waves/EU -> 128-reg cap, 2 WGs/CU
void gru_main(const float* __restrict__ e_wv, const float* __restrict__ m_wv,
              const __hip_bfloat16* __restrict__ wimg, float* __restrict__ out) {
  extern __shared__ char smem[];
  const int tid  = threadIdx.x;
  const int lane = tid & 63;
  const int wave = tid >> 6;       // 0..7
  const int wm = wave >> 2;        // 0..1 : 32-row half of 64-h tile
  const int wn = wave & 3;         // 0..3 : 32-col quarter of 128-n tile

  // XCD swizzle (bijective: 4096 % 8 == 0), ht fastest -> same X slab shared
  // by the 8 ht-WGs on one XCD's L2.
  const int wg  = blockIdx.x;
  const int swz = (wg & 7) * 512 + (wg >> 3);
  const int ht  = swz & 7;
  const int nt  = (swz >> 3) & 63;
  const int b   = swz >> 9;

  const int k0  = (tid & 15) << 2;   // 0..60  (4 k-rows per thread)
  const int n0s = (tid >> 4) << 2;   // 0..124 (4 n-cols per thread)

  const size_t batch_off = (size_t)b * HH * NN;
  const float* xm = m_wv + batch_off + (size_t)k0 * NN + nt * BN + n0s;
  const float* xe = e_wv + batch_off + (size_t)k0 * NN + nt * BN + n0s;
  const char*  wA = (const char*)wimg + (size_t)ht * NSTEPS * A_BYTES + tid * 16;

  f32x4 acc_r[2][2]  = {};
  f32x4 acc_z[2][2]  = {};
  f32x4 acc_in[2][2] = {};
  f32x4 acc_hn[2][2] = {};
  f32x4 bv[4];   // staged X f32: 4 k-rows x 4 n (16 regs)

  // Precomputed within-buffer LDS read offsets (R1-R7 verified swizzle math).
  int aoff[2], boff[2];
#pragma unroll
  for (int kb2 = 0; kb2 < 2; ++kb2) {
    const int ke2 = kb2 * 64 + ((lane >> 4) << 4);
    const int sw  = (lane & 7) << 4;
    aoff[kb2] = (wm * 32 + (lane & 15)) * 128 + (ke2 ^ sw);
    boff[kb2] = A_BYTES + (wn * 32 + (lane & 15)) * 128 + (ke2 ^ sw);
  }

  auto issue_A = [&](int s, char* nb) {   // DMA, zero VALU/LDS-write conflicts
    const char* gA = wA + (size_t)s * A_BYTES;
    char* lA = nb + tid * 16;
    gload_lds16(gA,          lA);
    gload_lds16(gA + 8192,   lA + 8192);
    gload_lds16(gA + 16384,  lA + 16384);
  };
  auto x_load = [&](const float* xs) {
#pragma unroll
    for (int i = 0; i < 4; ++i) bv[i] = *(const f32x4*)(xs + (size_t)i * NN);
  };
  auto write_X = [&](char* nb) {   // R1-pattern swizzled [n][k] writes (0-conflict verified)
    char* Bb = nb + A_BYTES;
#pragma unroll
    for (int j = 0; j < 4; ++j) {
      unsigned lo = cvt_pk_bf16(bv[0][j], bv[1][j]);   // k0,k0+1
      unsigned hi = cvt_pk_bf16(bv[2][j], bv[3][j]);   // k0+2,k0+3
      const int n = n0s + j;
      int off = n * 128 + ((k0 * 2) ^ ((n & 7) << 4));
      *(uint2*)(Bb + off) = make_uint2(lo, hi);
    }
  };
  auto compute_kb2 = [&](const char* cb, int kb2, bool firstHalf) {
    short8 bfr[2];
#pragma unroll
    for (int ni = 0; ni < 2; ++ni)
      bfr[ni] = *(const short8*)(cb + boff[kb2] + ni * 2048);
    {  // gate r
      short8 a0 = *(const short8*)(cb + aoff[kb2]);
      short8 a1 = *(const short8*)(cb + aoff[kb2] + 2048);
#pragma unroll
      for (int ni = 0; ni < 2; ++ni) {
        acc_r[0][ni] = MFMA16(a0, bfr[ni], acc_r[0][ni]);
        acc_r[1][ni] = MFMA16(a1, bfr[ni], acc_r[1][ni]);
      }
    }
    {  // gate z
      short8 a0 = *(const short8*)(cb + aoff[kb2] + 8192);
      short8 a1 = *(const short8*)(cb + aoff[kb2] + 8192 + 2048);
#pragma unroll
      for (int ni = 0; ni < 2; ++ni) {
        acc_z[0][ni] = MFMA16(a0, bfr[ni], acc_z[0][ni]);
        acc_z[1][ni] = MFMA16(a1, bfr[ni], acc_z[1][ni]);
      }
    }
    {  // gate n -> acc_in (m-phase) / acc_hn (e-phase)
      short8 a0 = *(const short8*)(cb + aoff[kb2] + 16384);
      short8 a1 = *(const short8*)(cb + aoff[kb2] + 16384 + 2048);
      if (firstHalf) {
#pragma unroll
        for (int ni = 0; ni < 2; ++ni) {
          acc_in[0][ni] = MFMA16(a0, bfr[ni], acc_in[0][ni]);
          acc_in[1][ni] = MFMA16(a1, bfr[ni], acc_in[1][ni]);
        }
      } else {
#pragma unroll
        for (int ni = 0; ni < 2; ++ni) {
          acc_hn[0][ni] = MFMA16(a0, bfr[ni], acc_hn[0][ni]);
          acc_hn[1][ni] = MFMA16(a1, bfr[ni], acc_hn[1][ni]);
        }
      }
    }
  };

  // prologue: stage step 0 into buf0
  issue_A(0, smem);
  x_load(xm);
  write_X(smem);
  __syncthreads();

#pragma unroll 1
  for (int s = 0; s < NSTEPS; ++s) {
    char* cb = smem + ((s & 1) ? BUF_BYTES : 0);
    char* nb = smem + ((s & 1) ? 0 : BUF_BYTES);
    const bool pre = (s < NSTEPS - 1);
    const bool firstHalf = (s < 8);

    if (pre) {
      const int t = s + 1;
      x_load((t < 8 ? xm : xe) + (size_t)(t & 7) * (64 * NN));  // in flight over compute
      issue_A(t, nb);
    }
    __builtin_amdgcn_s_setprio(1);
    compute_kb2(cb, 0, firstHalf);
    compute_kb2(cb, 1, firstHalf);
    __builtin_amdgcn_s_setprio(0);
    if (pre) write_X(nb);
    __syncthreads();
  }

  // epilogue: gates + blend (same math, wave tile 32h x 32n)
  const size_t obase = batch_off + (size_t)(ht * 64 + wm * 32) * NN + nt * BN + wn * 32;
  const float* ep = e_wv + obase;
  float* op = out + obase;
  const int rsub = (lane >> 4) << 2;
  const int csub = lane & 15;
#pragma unroll
  for (int mi = 0; mi < 2; ++mi)
#pragma unroll
    for (int ni = 0; ni < 2; ++ni) {
#pragma unroll
      for (int r = 0; r < 4; ++r) {
        size_t idx = (size_t)(mi * 16 + rsub + r) * NN + ni * 16 + csub;
        float pr  = acc_r[mi][ni][r];
        float pz  = acc_z[mi][ni][r];
        float vin = acc_in[mi][ni][r];
        float vhn = acc_hn[mi][ni][r];
        float rr  = 1.f / (1.f + __expf(-pr));
        float zz  = 1.f / (1.f + __expf(-pz));
        float ex  = __expf(2.f * (vin + rr * vhn));
        float nn2 = 1.f - 2.f / (ex + 1.f);      // tanh, inf-safe
        float ev  = ep[idx];
        op[idx] = (1.f - zz) * nn2 + zz * ev;
      }
    }
}

extern "C" void kernel_launch(void* const* d_in, const int* in_sizes, int n_in,
                              void* d_out, int out_size, void* d_ws, size_t ws_size,
                              hipStream_t stream) {
  const float* e_wv = (const float*)d_in[0];
  const float* m_wv = (const float*)d_in[1];
  const float* W_ih = (const float*)d_in[2];
  const float* W_hh = (const float*)d_in[3];
  float* out = (float*)d_out;
  __hip_bfloat16* wimg = (__hip_bfloat16*)d_ws;   // 3 MiB weight image

  (void)hipFuncSetAttribute((const void*)gru_main,
                            hipFuncAttributeMaxDynamicSharedMemorySize, LDS_TOTAL);

  prepack_w<<<(NBATCH * NSTEPS * 12288) / 256, 256, 0, stream>>>(W_ih, W_hh, wimg);
  gru_main<<<NBATCH * 8 * 64, THREADS, LDS_TOTAL, stream>>>(e_wv, m_wv, wimg, out);
}